// Round 5
// baseline (958.272 us; speedup 1.0000x reference)
//
#include <hip/hip_runtime.h>
#include <hip/hip_cooperative_groups.h>
#include <math.h>

#define BB 32
#define DD 1024
#define SS 4096
#define VVOUT 32003
#define PSTRIDE 1032          // per-wave partial: {M, L, pad[6], U[1024]}
#define NWAVE 2048            // 512 blocks x 4 waves

namespace cg = cooperative_groups;

__device__ __forceinline__ float sigmoidf_(float x) { return 1.f / (1.f + expf(-x)); }

// ---- phase bodies ----------------------------------------------------------

// One wave per output dim d. h[m][d] for all 32 m. gh = bhh since h_prev = 0.
template <bool GATHER>
__device__ void gru_body(int d, int lane,
                         const float* __restrict__ Xbase, const int* __restrict__ tokens,
                         const float* __restrict__ Wih, int ldw,
                         const float* __restrict__ bih, const float* __restrict__ bhh,
                         float* __restrict__ hout) {
  float4 wr_[4], wz_[4], wn_[4];
  const float* w0 = Wih + (size_t)d * ldw + 4 * lane;
  const float* w1 = Wih + (size_t)(1024 + d) * ldw + 4 * lane;
  const float* w2 = Wih + (size_t)(2048 + d) * ldw + 4 * lane;
#pragma unroll
  for (int c = 0; c < 4; c++) {
    wr_[c] = *(const float4*)(w0 + 256 * c);
    wz_[c] = *(const float4*)(w1 + 256 * c);
    wn_[c] = *(const float4*)(w2 + 256 * c);
  }
  int tok = 0;
  if (GATHER) tok = tokens[lane & 31];

  float vr = 0.f, vz = 0.f, vn = 0.f;
  for (int m = 0; m < BB; m++) {
    const float* xm;
    if (GATHER) {
      int t = __shfl(tok, m, 64);
      xm = Xbase + (size_t)t * DD + 4 * lane;
    } else {
      xm = Xbase + (size_t)m * DD + 4 * lane;
    }
    float pr = 0.f, pz = 0.f, pn = 0.f;
#pragma unroll
    for (int c = 0; c < 4; c++) {
      float4 x4 = *(const float4*)(xm + 256 * c);
      pr += wr_[c].x * x4.x + wr_[c].y * x4.y + wr_[c].z * x4.z + wr_[c].w * x4.w;
      pz += wz_[c].x * x4.x + wz_[c].y * x4.y + wz_[c].z * x4.z + wz_[c].w * x4.w;
      pn += wn_[c].x * x4.x + wn_[c].y * x4.y + wn_[c].z * x4.z + wn_[c].w * x4.w;
    }
#pragma unroll
    for (int off = 32; off; off >>= 1) {
      pr += __shfl_xor(pr, off, 64);
      pz += __shfl_xor(pz, off, 64);
      pn += __shfl_xor(pn, off, 64);
    }
    if (lane == m) { vr = pr; vz = pz; vn = pn; }
  }
  if (lane < BB) {
    float r = sigmoidf_(vr + bih[d] + bhh[d]);
    float z = sigmoidf_(vz + bih[1024 + d] + bhh[1024 + d]);
    float n = tanhf(vn + bih[2048 + d] + r * bhh[2048 + d]);
    hout[(size_t)lane * DD + d] = (1.f - z) * n;
  }
}

// One wave per (b, 64-row span): online-softmax partial, register-only.
__device__ void attn_body(int gw, int lane,
                          const float* __restrict__ ht, const float* __restrict__ enc,
                          const int* __restrict__ mask, float* __restrict__ part) {
  int b = gw >> 6;
  int s0 = (gw & 63) * 64;
  const float* encb = enc + (size_t)b * SS * DD;
  const float* htb = ht + (size_t)b * DD;
  const int* mb = mask + (size_t)b * SS + s0;

  float4 h4[4];
#pragma unroll
  for (int j = 0; j < 4; j++) h4[j] = *(const float4*)(htb + 256 * j + 4 * lane);

  float4 acc[4];
#pragma unroll
  for (int j = 0; j < 4; j++) acc[j] = make_float4(0.f, 0.f, 0.f, 0.f);
  float mw = -INFINITY, lw = 0.f;

  for (int ii = 0; ii < 32; ii++) {
    int s = 2 * ii;
    int mk0 = mb[s], mk1 = mb[s + 1];
    const float* er = encb + (size_t)(s0 + s) * DD + 4 * lane;
    float4 e0[4], e1[4];
#pragma unroll
    for (int j = 0; j < 4; j++) {
      e0[j] = *(const float4*)(er + 256 * j);
      e1[j] = *(const float4*)(er + DD + 256 * j);
    }
    float p0 = 0.f, p1 = 0.f;
#pragma unroll
    for (int j = 0; j < 4; j++) {
      p0 += e0[j].x * h4[j].x + e0[j].y * h4[j].y + e0[j].z * h4[j].z + e0[j].w * h4[j].w;
      p1 += e1[j].x * h4[j].x + e1[j].y * h4[j].y + e1[j].z * h4[j].z + e1[j].w * h4[j].w;
    }
#pragma unroll
    for (int off = 32; off; off >>= 1) {
      p0 += __shfl_xor(p0, off, 64);
      p1 += __shfl_xor(p1, off, 64);
    }
    if (!mk0) p0 = -INFINITY;
    if (!mk1) p1 = -INFINITY;
    float mn = fmaxf(mw, fmaxf(p0, p1));
    if (mn > -INFINITY) {
      float scv = (mw > -INFINITY) ? __expf(mw - mn) : 0.f;
      float a0 = __expf(p0 - mn);
      float a1 = __expf(p1 - mn);
      lw = lw * scv + a0 + a1;
#pragma unroll
      for (int j = 0; j < 4; j++) {
        acc[j].x = acc[j].x * scv + a0 * e0[j].x + a1 * e1[j].x;
        acc[j].y = acc[j].y * scv + a0 * e0[j].y + a1 * e1[j].y;
        acc[j].z = acc[j].z * scv + a0 * e0[j].z + a1 * e1[j].z;
        acc[j].w = acc[j].w * scv + a0 * e0[j].w + a1 * e1[j].w;
      }
      mw = mn;
    }
  }

  float* P = part + (size_t)gw * PSTRIDE;
  if (lane == 0) { P[0] = mw; P[1] = lw; }
#pragma unroll
  for (int j = 0; j < 4; j++) *(float4*)&P[8 + 256 * j + 4 * lane] = acc[j];
}

// Block b combines its 64 partials; writes xcat = [h_t | summary].
__device__ void reduce_body(int b, int tid,
                            const float* __restrict__ part, const float* __restrict__ ht,
                            float* __restrict__ xcat) {
  const float* Pb = part + (size_t)b * 64 * PSTRIDE;
  float M = -INFINITY;
  for (int c = 0; c < 64; c++) M = fmaxf(M, Pb[c * PSTRIDE]);
  float L = 0.f;
  for (int c = 0; c < 64; c++) {
    float mc = Pb[c * PSTRIDE];
    if (mc > -INFINITY) L += Pb[c * PSTRIDE + 1] * __expf(mc - M);
  }
  float inv = (L > 0.f) ? 1.f / L : 0.f;
  float4 u = make_float4(0.f, 0.f, 0.f, 0.f);
  for (int c = 0; c < 64; c++) {
    float mc = Pb[c * PSTRIDE];
    if (mc > -INFINITY) {
      float s_ = __expf(mc - M);
      float4 a = *(const float4*)&Pb[c * PSTRIDE + 8 + 4 * tid];
      u.x += s_ * a.x; u.y += s_ * a.y; u.z += s_ * a.z; u.w += s_ * a.w;
    }
  }
  u.x *= inv; u.y *= inv; u.z *= inv; u.w *= inv;
  *(float4*)&xcat[(size_t)b * 2048 + 1024 + 4 * tid] = u;
  *(float4*)&xcat[(size_t)b * 2048 + 4 * tid] = *(const float4*)&ht[(size_t)b * DD + 4 * tid];
}

// One wave per output n. opre[m][n] = bias[n] + xcat[m] . W[n]
__device__ void preout_body(int n, int lane,
                            const float* __restrict__ xcat, const float* __restrict__ W,
                            const float* __restrict__ bias, float* __restrict__ Y) {
  float4 wreg[8];
  const float* wr = W + (size_t)n * 2048 + 4 * lane;
#pragma unroll
  for (int c = 0; c < 8; c++) wreg[c] = *(const float4*)(wr + 256 * c);
  float vm = 0.f;
  for (int m = 0; m < BB; m++) {
    const float* xm = xcat + (size_t)m * 2048 + 4 * lane;
    float p = 0.f;
#pragma unroll
    for (int c = 0; c < 8; c++) {
      float4 x4 = *(const float4*)(xm + 256 * c);
      p += wreg[c].x * x4.x + wreg[c].y * x4.y + wreg[c].z * x4.z + wreg[c].w * x4.w;
    }
#pragma unroll
    for (int off = 32; off; off >>= 1) p += __shfl_xor(p, off, 64);
    if (lane == m) vm = p;
  }
  if (lane < BB) Y[(size_t)lane * DD + n] = vm + bias[n];
}

// One wave per 16 vocab rows; 4 lanes/row.
__device__ void logits_body(int gw, int lane,
                            const float* __restrict__ X, const float* __restrict__ W,
                            const float* __restrict__ bias, float* __restrict__ Y) {
  int c = lane & 3;
  int r = gw * 16 + (lane >> 2);
  bool valid = r < VVOUT;
  int rr = valid ? r : VVOUT - 1;
  const float* wrow = W + (size_t)rr * DD + 4 * c;
  const float* xp = X + 4 * c;
  float acc[BB];
#pragma unroll
  for (int m = 0; m < BB; m++) acc[m] = 0.f;
#pragma unroll 2
  for (int kk = 0; kk < DD; kk += 16) {
    float4 w4 = *(const float4*)(wrow + kk);
#pragma unroll
    for (int m = 0; m < BB; m++) {
      float4 x4 = *(const float4*)(xp + (size_t)m * DD + kk);
      acc[m] = fmaf(w4.x, x4.x, fmaf(w4.y, x4.y, fmaf(w4.z, x4.z, fmaf(w4.w, x4.w, acc[m]))));
    }
  }
  float b = valid ? bias[r] : 0.f;
#pragma unroll
  for (int m = 0; m < BB; m++) {
    float v = acc[m];
    v += __shfl_xor(v, 1, 64);
    v += __shfl_xor(v, 2, 64);
    if (c == 0 && valid) Y[(size_t)m * VVOUT + r] = v + b;
  }
}

// ---- the monolithic kernel -------------------------------------------------

__global__ __launch_bounds__(256, 2) void mono(
    const int* __restrict__ tokens, const float* __restrict__ enc,
    const int* __restrict__ encmask, const float* __restrict__ emb,
    const float* __restrict__ Wih0, const float* __restrict__ bih0, const float* __restrict__ bhh0,
    const float* __restrict__ Wih1, const float* __restrict__ bih1, const float* __restrict__ bhh1,
    const float* __restrict__ preoutW, const float* __restrict__ preoutb,
    const float* __restrict__ outW, const float* __restrict__ outb,
    float* __restrict__ out, float* __restrict__ h, float* __restrict__ ht,
    float* __restrict__ part, float* __restrict__ xcat, float* __restrict__ opre,
    int phases, int coop) {
  cg::grid_group grid = cg::this_grid();
  int w = threadIdx.x >> 6, lane = threadIdx.x & 63;
  int gw = blockIdx.x * 4 + w;

  if (phases & 1) {
    if (gw < DD) gru_body<true>(gw, lane, emb, tokens, Wih0, 2048, bih0, bhh0, h);
  }
  if (coop) { __threadfence(); grid.sync(); }
  if (phases & 2) {
    if (gw < DD) gru_body<false>(gw, lane, h, tokens, Wih1, 1024, bih1, bhh1, ht);
  }
  if (coop) { __threadfence(); grid.sync(); }
  if (phases & 4) {
    attn_body(gw, lane, ht, enc, encmask, part);
  }
  if (coop) { __threadfence(); grid.sync(); }
  if (phases & 8) {
    if (blockIdx.x < BB) reduce_body(blockIdx.x, threadIdx.x, part, ht, xcat);
  }
  if (coop) { __threadfence(); grid.sync(); }
  if (phases & 16) {
    if (gw < DD) preout_body(gw, lane, xcat, preoutW, preoutb, opre);
  }
  if (coop) { __threadfence(); grid.sync(); }
  if (phases & 32) {
    logits_body(gw, lane, opre, outW, outb, out);
  }
}

extern "C" void kernel_launch(void* const* d_in, const int* in_sizes, int n_in,
                              void* d_out, int out_size, void* d_ws, size_t ws_size,
                              hipStream_t stream) {
  const int*   tokens  = (const int*)d_in[0];
  const float* enc     = (const float*)d_in[1];
  const int*   encmask = (const int*)d_in[2];
  const float* emb     = (const float*)d_in[3];
  const float* Wih0    = (const float*)d_in[4];
  const float* bih0    = (const float*)d_in[6];
  const float* bhh0    = (const float*)d_in[7];
  const float* Wih1    = (const float*)d_in[8];
  const float* bih1    = (const float*)d_in[10];
  const float* bhh1    = (const float*)d_in[11];
  const float* preoutW = (const float*)d_in[12];
  const float* preoutb = (const float*)d_in[13];
  const float* outW    = (const float*)d_in[14];
  const float* outb    = (const float*)d_in[15];
  float* out = (float*)d_out;
  float* ws  = (float*)d_ws;

  float* h    = ws;                          // 32*1024
  float* ht   = h + 32 * 1024;               // 32*1024
  float* part = ht + 32 * 1024;              // NWAVE*PSTRIDE (~8.4 MB)
  float* xcat = part + (size_t)NWAVE * PSTRIDE;  // 32*2048
  float* opre = xcat + 32 * 2048;            // 32*1024

  int phases = 63, coop = 1;
  void* args[] = { (void*)&tokens, (void*)&enc, (void*)&encmask, (void*)&emb,
                   (void*)&Wih0, (void*)&bih0, (void*)&bhh0,
                   (void*)&Wih1, (void*)&bih1, (void*)&bhh1,
                   (void*)&preoutW, (void*)&preoutb, (void*)&outW, (void*)&outb,
                   (void*)&out, (void*)&h, (void*)&ht, (void*)&part, (void*)&xcat, (void*)&opre,
                   (void*)&phases, (void*)&coop };
  hipError_t e = hipLaunchCooperativeKernel((const void*)mono, dim3(512), dim3(256),
                                            args, 0, stream);
  if (e != hipSuccess) {
    // fallback: six ordinary launches, stream order replaces grid.sync
    for (int p = 0; p < 6; p++) {
      mono<<<512, 256, 0, stream>>>(tokens, enc, encmask, emb,
                                    Wih0, bih0, bhh0, Wih1, bih1, bhh1,
                                    preoutW, preoutb, outW, outb,
                                    out, h, ht, part, xcat, opre, 1 << p, 0);
    }
  }
}

// Round 6
// 428.554 us; speedup vs baseline: 2.2361x; 2.2361x over previous
//
#include <hip/hip_runtime.h>
#include <math.h>

#define BB 32
#define DD 1024
#define SS 4096
#define VVOUT 32003
#define NCH 128              // chunks per batch row (32 rows per chunk)
#define PSTRIDE 1032         // per-chunk partial: {M, L, pad[6], U[1024]}

__device__ __forceinline__ float sigmoidf_(float x) { return 1.f / (1.f + expf(-x)); }

// ---------------- GRU (one wave per output dim d; h_prev = 0) ---------------
template <bool GATHER>
__global__ __launch_bounds__(256, 4) void gru_fused(
    const float* __restrict__ Xbase, const int* __restrict__ tokens,
    const float* __restrict__ Wih, int ldw,
    const float* __restrict__ bih, const float* __restrict__ bhh,
    float* __restrict__ hout) {
  int d = (blockIdx.x * 256 + threadIdx.x) >> 6;
  int lane = threadIdx.x & 63;
  float4 wr_[4], wz_[4], wn_[4];
  const float* w0 = Wih + (size_t)d * ldw + 4 * lane;
  const float* w1 = Wih + (size_t)(1024 + d) * ldw + 4 * lane;
  const float* w2 = Wih + (size_t)(2048 + d) * ldw + 4 * lane;
#pragma unroll
  for (int c = 0; c < 4; c++) {
    wr_[c] = *(const float4*)(w0 + 256 * c);
    wz_[c] = *(const float4*)(w1 + 256 * c);
    wn_[c] = *(const float4*)(w2 + 256 * c);
  }
  int tok = 0;
  if (GATHER) tok = tokens[lane & 31];
  float vr = 0.f, vz = 0.f, vn = 0.f;
  for (int m = 0; m < BB; m++) {
    const float* xm;
    if (GATHER) {
      int t = __shfl(tok, m, 64);
      xm = Xbase + (size_t)t * DD + 4 * lane;
    } else {
      xm = Xbase + (size_t)m * DD + 4 * lane;
    }
    float pr = 0.f, pz = 0.f, pn = 0.f;
#pragma unroll
    for (int c = 0; c < 4; c++) {
      float4 x4 = *(const float4*)(xm + 256 * c);
      pr += wr_[c].x * x4.x + wr_[c].y * x4.y + wr_[c].z * x4.z + wr_[c].w * x4.w;
      pz += wz_[c].x * x4.x + wz_[c].y * x4.y + wz_[c].z * x4.z + wz_[c].w * x4.w;
      pn += wn_[c].x * x4.x + wn_[c].y * x4.y + wn_[c].z * x4.z + wn_[c].w * x4.w;
    }
#pragma unroll
    for (int off = 32; off; off >>= 1) {
      pr += __shfl_xor(pr, off, 64);
      pz += __shfl_xor(pz, off, 64);
      pn += __shfl_xor(pn, off, 64);
    }
    if (lane == m) { vr = pr; vz = pz; vn = pn; }
  }
  if (lane < BB) {
    float r = sigmoidf_(vr + bih[d] + bhh[d]);
    float z = sigmoidf_(vz + bih[1024 + d] + bhh[1024 + d]);
    float n = tanhf(vn + bih[2048 + d] + r * bhh[2048 + d]);
    hout[(size_t)lane * DD + d] = (1.f - z) * n;
  }
}

// ---------------- attention partial (one pass over enc) ---------------------
__device__ __forceinline__ void attn_step(
    const float4 (&e0)[4], const float4 (&e1)[4], int mk0, int mk1,
    const float4 (&h4)[4], float4 (&acc)[4], float& mw, float& lw) {
  float p0 = 0.f, p1 = 0.f;
#pragma unroll
  for (int j = 0; j < 4; j++) {
    p0 += e0[j].x * h4[j].x + e0[j].y * h4[j].y + e0[j].z * h4[j].z + e0[j].w * h4[j].w;
    p1 += e1[j].x * h4[j].x + e1[j].y * h4[j].y + e1[j].z * h4[j].z + e1[j].w * h4[j].w;
  }
#pragma unroll
  for (int off = 32; off; off >>= 1) {
    p0 += __shfl_xor(p0, off, 64);
    p1 += __shfl_xor(p1, off, 64);
  }
  if (!mk0) p0 = -INFINITY;
  if (!mk1) p1 = -INFINITY;
  float mn = fmaxf(mw, fmaxf(p0, p1));
  if (mn > -INFINITY) {
    float scv = (mw > -INFINITY) ? __expf(mw - mn) : 0.f;
    float a0 = __expf(p0 - mn);
    float a1 = __expf(p1 - mn);
    lw = lw * scv + a0 + a1;
#pragma unroll
    for (int j = 0; j < 4; j++) {
      acc[j].x = acc[j].x * scv + a0 * e0[j].x + a1 * e1[j].x;
      acc[j].y = acc[j].y * scv + a0 * e0[j].y + a1 * e1[j].y;
      acc[j].z = acc[j].z * scv + a0 * e0[j].z + a1 * e1[j].z;
      acc[j].w = acc[j].w * scv + a0 * e0[j].w + a1 * e1[j].w;
    }
    mw = mn;
  }
}

#define LOADPAIR(d0, d1, p)                          \
  {                                                  \
    const float* _p = (p);                           \
    _Pragma("unroll")                                \
    for (int j = 0; j < 4; j++) {                    \
      d0[j] = *(const float4*)(_p + 256 * j);        \
      d1[j] = *(const float4*)(_p + DD + 256 * j);   \
    }                                                \
  }

// Block = (b, chunk of 32 rows); 4 waves x 8 rows; 2-row groups, 2-deep pipeline.
__global__ __launch_bounds__(256, 4) void attn_partial(
    const float* __restrict__ ht, const float* __restrict__ enc,
    const int* __restrict__ mask, float* __restrict__ part) {
  int b = blockIdx.x;
  int chunk = blockIdx.y;
  int w = threadIdx.x >> 6;
  int l = threadIdx.x & 63;
  int s0 = chunk * 32;

  __shared__ int smask[32];
  __shared__ float sml[4][2];
  __shared__ float sacc[4][1024];
  if (threadIdx.x < 32) smask[threadIdx.x] = mask[(size_t)b * SS + s0 + threadIdx.x];

  const float* htb = ht + (size_t)b * DD;
  float4 h4[4];
#pragma unroll
  for (int j = 0; j < 4; j++) h4[j] = *(const float4*)(htb + 256 * j + 4 * l);
  __syncthreads();

  int r0 = w * 8;
  int mk[8];
#pragma unroll
  for (int i = 0; i < 8; i++) mk[i] = smask[r0 + i];

  const float* base = enc + (size_t)b * SS * DD + (size_t)(s0 + r0) * DD + 4 * l;

  float4 acc[4];
#pragma unroll
  for (int j = 0; j < 4; j++) acc[j] = make_float4(0.f, 0.f, 0.f, 0.f);
  float mw = -INFINITY, lw = 0.f;

  float4 A0[4], A1[4], B0[4], B1[4];
  LOADPAIR(A0, A1, base);                 // rows 0,1
  LOADPAIR(B0, B1, base + 2 * DD);        // rows 2,3
  attn_step(A0, A1, mk[0], mk[1], h4, acc, mw, lw);
  LOADPAIR(A0, A1, base + 4 * DD);        // rows 4,5
  attn_step(B0, B1, mk[2], mk[3], h4, acc, mw, lw);
  LOADPAIR(B0, B1, base + 6 * DD);        // rows 6,7
  attn_step(A0, A1, mk[4], mk[5], h4, acc, mw, lw);
  attn_step(B0, B1, mk[6], mk[7], h4, acc, mw, lw);

  if (l == 0) { sml[w][0] = mw; sml[w][1] = lw; }
#pragma unroll
  for (int j = 0; j < 4; j++) *(float4*)&sacc[w][256 * j + 4 * l] = acc[j];
  __syncthreads();

  float M = fmaxf(fmaxf(sml[0][0], sml[1][0]), fmaxf(sml[2][0], sml[3][0]));
  float L = 0.f;
  float scw[4];
#pragma unroll
  for (int ww = 0; ww < 4; ww++) {
    float mm = sml[ww][0];
    float s_ = (mm == -INFINITY) ? 0.f : __expf(mm - M);
    scw[ww] = s_;
    L += sml[ww][1] * s_;
  }
  float* P = part + (size_t)(b * NCH + chunk) * PSTRIDE;
  int tid = threadIdx.x;
  if (tid == 0) { P[0] = M; P[1] = L; }
  float4 u = make_float4(0.f, 0.f, 0.f, 0.f);
#pragma unroll
  for (int ww = 0; ww < 4; ww++) {
    float4 a = *(const float4*)&sacc[ww][4 * tid];
    u.x += scw[ww] * a.x; u.y += scw[ww] * a.y;
    u.z += scw[ww] * a.z; u.w += scw[ww] * a.w;
  }
  *(float4*)&P[8 + 4 * tid] = u;
}

// Combine NCH partials per b; build xcat = [h_t | summary]
__global__ __launch_bounds__(256) void attn_reduce(
    const float* __restrict__ part, const float* __restrict__ ht,
    float* __restrict__ xcat) {
  int b = blockIdx.x;
  int tid = threadIdx.x;
  const float* Pb = part + (size_t)b * NCH * PSTRIDE;
  float M = -INFINITY;
  for (int c = 0; c < NCH; c++) M = fmaxf(M, Pb[c * PSTRIDE]);
  float L = 0.f;
  for (int c = 0; c < NCH; c++) {
    float mc = Pb[c * PSTRIDE];
    if (mc > -INFINITY) L += Pb[c * PSTRIDE + 1] * __expf(mc - M);
  }
  float inv = (L > 0.f) ? 1.f / L : 0.f;
  float4 u = make_float4(0.f, 0.f, 0.f, 0.f);
  for (int c = 0; c < NCH; c++) {
    float mc = Pb[c * PSTRIDE];
    if (mc > -INFINITY) {
      float s_ = __expf(mc - M);
      float4 a = *(const float4*)&Pb[c * PSTRIDE + 8 + 4 * tid];
      u.x += s_ * a.x; u.y += s_ * a.y; u.z += s_ * a.z; u.w += s_ * a.w;
    }
  }
  u.x *= inv; u.y *= inv; u.z *= inv; u.w *= inv;
  *(float4*)&xcat[(size_t)b * 2048 + 1024 + 4 * tid] = u;
  *(float4*)&xcat[(size_t)b * 2048 + 4 * tid] = *(const float4*)&ht[(size_t)b * DD + 4 * tid];
}

// ---------------- preout (one wave per output n, K=2048) --------------------
__global__ __launch_bounds__(256, 4) void preout_fused(
    const float* __restrict__ xcat, const float* __restrict__ W,
    const float* __restrict__ bias, float* __restrict__ Y) {
  int n = (blockIdx.x * 256 + threadIdx.x) >> 6;
  int lane = threadIdx.x & 63;
  float4 wreg[8];
  const float* wr = W + (size_t)n * 2048 + 4 * lane;
#pragma unroll
  for (int c = 0; c < 8; c++) wreg[c] = *(const float4*)(wr + 256 * c);
  float vm = 0.f;
  for (int m = 0; m < BB; m++) {
    const float* xm = xcat + (size_t)m * 2048 + 4 * lane;
    float p = 0.f;
#pragma unroll
    for (int c = 0; c < 8; c++) {
      float4 x4 = *(const float4*)(xm + 256 * c);
      p += wreg[c].x * x4.x + wreg[c].y * x4.y + wreg[c].z * x4.z + wreg[c].w * x4.w;
    }
#pragma unroll
    for (int off = 32; off; off >>= 1) p += __shfl_xor(p, off, 64);
    if (lane == m) vm = p;
  }
  if (lane < BB) Y[(size_t)lane * DD + n] = vm + bias[n];
}

// ---------------- logits ----------------------------------------------------
__global__ void fill_bias(float* __restrict__ Y, const float* __restrict__ bias,
                          int N, int total) {
  int i = blockIdx.x * 256 + threadIdx.x;
  if (i < total) Y[i] = bias[i - (i / N) * N];
}

// 16 rows/wave, 4 lanes/row, k-split 2 via gridDim.y, atomics into prefilled Y.
__global__ __launch_bounds__(256, 4) void logits_mm(
    const float* __restrict__ X, const float* __restrict__ W,
    float* __restrict__ Y) {
  int lane = threadIdx.x & 63;
  int w = threadIdx.x >> 6;
  int c = lane & 3;
  int r = (blockIdx.x * 4 + w) * 16 + (lane >> 2);
  bool valid = r < VVOUT;
  int rr = valid ? r : VVOUT - 1;
  int k0 = blockIdx.y * 512;
  const float* wrow = W + (size_t)rr * DD + k0 + 4 * c;
  const float* xp = X + k0 + 4 * c;
  float acc[BB];
#pragma unroll
  for (int m = 0; m < BB; m++) acc[m] = 0.f;
#pragma unroll 4
  for (int kk = 0; kk < 512; kk += 16) {
    float4 w4 = *(const float4*)(wrow + kk);
#pragma unroll
    for (int m = 0; m < BB; m++) {
      float4 x4 = *(const float4*)(xp + (size_t)m * DD + kk);
      acc[m] = fmaf(w4.x, x4.x, fmaf(w4.y, x4.y, fmaf(w4.z, x4.z, fmaf(w4.w, x4.w, acc[m]))));
    }
  }
#pragma unroll
  for (int m = 0; m < BB; m++) {
    float v = acc[m];
    v += __shfl_xor(v, 1, 64);
    v += __shfl_xor(v, 2, 64);
    if (c == 0 && valid) atomicAdd(&Y[(size_t)m * VVOUT + r], v);
  }
}

extern "C" void kernel_launch(void* const* d_in, const int* in_sizes, int n_in,
                              void* d_out, int out_size, void* d_ws, size_t ws_size,
                              hipStream_t stream) {
  const int*   tokens  = (const int*)d_in[0];
  const float* enc     = (const float*)d_in[1];
  const int*   encmask = (const int*)d_in[2];
  const float* emb     = (const float*)d_in[3];
  const float* Wih0    = (const float*)d_in[4];
  const float* bih0    = (const float*)d_in[6];
  const float* bhh0    = (const float*)d_in[7];
  const float* Wih1    = (const float*)d_in[8];
  const float* bih1    = (const float*)d_in[10];
  const float* bhh1    = (const float*)d_in[11];
  const float* preoutW = (const float*)d_in[12];
  const float* preoutb = (const float*)d_in[13];
  const float* outW    = (const float*)d_in[14];
  const float* outb    = (const float*)d_in[15];
  float* out = (float*)d_out;
  float* ws  = (float*)d_ws;

  float* h    = ws;                            // 32*1024
  float* ht   = h + 32 * 1024;                 // 32*1024
  float* part = ht + 32 * 1024;                // 32*128*1032 (~16.9 MB)
  float* xcat = part + (size_t)32 * NCH * PSTRIDE;
  float* opre = xcat + 32 * 2048;              // 32*1024

  gru_fused<true><<<256, 256, 0, stream>>>(emb, tokens, Wih0, 2048, bih0, bhh0, h);
  gru_fused<false><<<256, 256, 0, stream>>>(h, tokens, Wih1, 1024, bih1, bhh1, ht);

  attn_partial<<<dim3(BB, NCH), 256, 0, stream>>>(ht, enc, encmask, part);
  attn_reduce<<<BB, 256, 0, stream>>>(part, ht, xcat);

  preout_fused<<<256, 256, 0, stream>>>(xcat, preoutW, preoutb, opre);

  fill_bias<<<(BB * VVOUT + 255) / 256, 256, 0, stream>>>(out, outb, VVOUT, BB * VVOUT);
  logits_mm<<<dim3(501, 2), 256, 0, stream>>>(opre, outW, out);
}